// Round 12
// baseline (81.696 us; speedup 1.0000x reference)
//
#include <hip/hip_runtime.h>

// Problem constants (match reference)
#define BB 16
#define CC 8
#define HW (512 * 512)          // pixels per image
#define IGNORE_IDX 255
#define EPS_F 1e-5f
#define MINPIX 10.0f

// Launch config
#define BPI 128                 // blocks per image
#define NTHR 256
#define NBLK (BB * BPI)         // 2048 blocks
#define PPB (HW / BPI)          // 2048 pixels per block -> 2 iters of 1024

// ws accumulators (all float, all communication via device-scope atomics):
//   [0   .. 128)  I[b*8+c]   (dice intersection)
//   [128 .. 256)  P[b*8+c]   (prob sum)
//   [256 .. 384)  T[b*8+c]   (target count)
//   [384]         CE sum
//   [385]         valid-count sum
//   [386]         u32 arrival counter
// hipMemsetAsync zeroes [0..387) each call (graph-capturable node, R7-proven).
#define ACC_I   0
#define ACC_P   128
#define ACC_T   256
#define ACC_CE  384
#define ACC_CN  385
#define CTR_IDX 386

__device__ __forceinline__ float wave_red(float v) {
#pragma unroll
    for (int o = 32; o > 0; o >>= 1) v += __shfl_xor(v, o, 64);
    return v;
}

// NOTE (R8): no min-waves hint — __launch_bounds__(256,3) forced VGPR 232->84
// via scratch spills (+440 MB spill traffic, 8x slower).
// NOTE (R9/R11): latency-bound; #pragma unroll 1 keeps one iteration's 9 loads
// in flight -> VGPR 48 -> max occupancy tier. 76.9 -> 49.6 us same container.
// NOTE (R7): NO __threadfence() anywhere — device-scope fences caused XCD-L2
// writeback storms (330 GB/s, 5x slowdown). All cross-block communication here
// is via device-scope atomics (coherent by default, m20), zero fences.
__global__ __launch_bounds__(NTHR) void focal_fused(
    const float* __restrict__ logits, const int* __restrict__ tgt,
    float* __restrict__ ws, float* __restrict__ out)
{
    const int b     = blockIdx.x / BPI;
    const int chunk = blockIdx.x % BPI;
    const float* base = logits + (size_t)b * (CC * HW);
    const int*   tb   = tgt    + (size_t)b * HW;
    const int start = chunk * PPB;

    float psum[8]  = {0.f,0.f,0.f,0.f,0.f,0.f,0.f,0.f};
    float inter[8] = {0.f,0.f,0.f,0.f,0.f,0.f,0.f,0.f};
    int   tcnt[8]  = {0,0,0,0,0,0,0,0};
    float ce = 0.f;
    int   cnt = 0;

#pragma unroll 1
    for (int it = 0; it < PPB; it += NTHR * 4) {
        const int pix = start + it + (int)threadIdx.x * 4;
        const int4 t4 = *reinterpret_cast<const int4*>(tb + pix);
        float4 v[8];
#pragma unroll
        for (int c = 0; c < 8; ++c)
            v[c] = *reinterpret_cast<const float4*>(base + (size_t)c * HW + pix);

#pragma unroll
        for (int j = 0; j < 4; ++j) {
            const int t = (&t4.x)[j];
            float x[8];
#pragma unroll
            for (int c = 0; c < 8; ++c) x[c] = (&v[c].x)[j];

            float m = x[0];
#pragma unroll
            for (int c = 1; c < 8; ++c) m = fmaxf(m, x[c]);

            float e[8];
            float s = 0.f;
#pragma unroll
            for (int c = 0; c < 8; ++c) { e[c] = __expf(x[c] - m); s += e[c]; }
            const float inv = 1.0f / s;

            const bool valid = (t != IGNORE_IDX);
            float xt = 0.f, et = 0.f;
#pragma unroll
            for (int c = 0; c < 8; ++c) {
                const float pc = e[c] * inv;
                psum[c] += valid ? pc : 0.f;
                const bool hit = valid && (t == c);
                inter[c] += hit ? pc : 0.f;
                tcnt[c]  += hit ? 1 : 0;
                xt = (t == c) ? x[c] : xt;   // compile-time-unrolled select
                et = (t == c) ? e[c] : et;
            }
            const float pt    = et * inv;
            const float logpt = (xt - m) - __logf(s);
            const float omp   = 1.f - pt;
            ce  += valid ? -(omp * omp) * logpt : 0.f;
            cnt += valid ? 1 : 0;
        }
    }

    // ---- block reduction: wave shuffle -> LDS ----
    __shared__ float sm[4][26];
    const int wave = threadIdx.x >> 6;
    const int lane = threadIdx.x & 63;

    float red[26];
#pragma unroll
    for (int c = 0; c < 8; ++c) red[c]      = inter[c];
#pragma unroll
    for (int c = 0; c < 8; ++c) red[8 + c]  = psum[c];
#pragma unroll
    for (int c = 0; c < 8; ++c) red[16 + c] = (float)tcnt[c];
    red[24] = ce;
    red[25] = (float)cnt;

#pragma unroll
    for (int k = 0; k < 26; ++k) {
        const float r = wave_red(red[k]);
        if (lane == 0) sm[wave][k] = r;
    }
    __syncthreads();

    const int tid = threadIdx.x;
    // ---- per-block partials -> global accumulators via device-scope atomics
    if (tid < 26) {
        const float tot = sm[0][tid] + sm[1][tid] + sm[2][tid] + sm[3][tid];
        if (tid < 8)
            atomicAdd(&ws[ACC_I + b * CC + tid], tot);
        else if (tid < 16)
            atomicAdd(&ws[ACC_P + b * CC + (tid - 8)], tot);
        else if (tid < 24)
            atomicAdd(&ws[ACC_T + b * CC + (tid - 16)], tot);
        else if (tid == 24)
            atomicAdd(&ws[ACC_CE], tot);
        else
            atomicAdd(&ws[ACC_CN], tot);
    }

    // __syncthreads drains vmcnt(0): all 26 atomics complete at the coherent
    // point before any thread proceeds -> counter increment orders after data.
    __syncthreads();
    __shared__ int lastSh;
    if (tid == 0) {
        unsigned old = atomicAdd(reinterpret_cast<unsigned*>(ws) + CTR_IDX, 1u);
        lastSh = (old == (unsigned)(NBLK - 1)) ? 1 : 0;
    }
    __syncthreads();
    if (!lastSh) return;

    // ---- last arriving block: fold 386 accumulators (atomic reads = coherent)
    float dval = 0.f;
    float ceL = 0.f, cnL = 0.f;
    if (tid < BB * CC) {
        const int c = tid & 7;
        const float I = atomicAdd(&ws[ACC_I + tid], 0.f);
        const float P = atomicAdd(&ws[ACC_P + tid], 0.f);
        const float T = atomicAdd(&ws[ACC_T + tid], 0.f);
        if (c >= 1 && T > MINPIX)
            dval = 1.f - (2.f * I + EPS_F) / (P + T + EPS_F);
    } else if (tid == BB * CC) {
        ceL = atomicAdd(&ws[ACC_CE], 0.f);
    } else if (tid == BB * CC + 1) {
        cnL = atomicAdd(&ws[ACC_CN], 0.f);
    }

    dval = wave_red(dval);                 // waves 0,1 hold the 128 dice terms

    __shared__ float sd[4];
    __shared__ float sCE, sCN;
    if (lane == 0) sd[wave] = dval;
    if (tid == BB * CC)     sCE = ceL;
    if (tid == BB * CC + 1) sCN = cnL;
    __syncthreads();

    if (tid == 0) {
        const float D = sd[0] + sd[1];     // waves 2,3 contributed nothing
        out[0] = (sCE / sCN) + 0.1f * (D / ((CC - 1) * (float)BB));
    }
}

extern "C" void kernel_launch(void* const* d_in, const int* in_sizes, int n_in,
                              void* d_out, int out_size, void* d_ws, size_t ws_size,
                              hipStream_t stream)
{
    const float* logits = (const float*)d_in[0];
    const int*   tgt    = (const int*)d_in[1];
    float*       ws     = (float*)d_ws;
    float*       out    = (float*)d_out;

    // Zero the 386 float accumulators + u32 counter (1548 B, capturable node).
    hipMemsetAsync(d_ws, 0, (CTR_IDX + 1) * sizeof(float), stream);
    focal_fused<<<NBLK, NTHR, 0, stream>>>(logits, tgt, ws, out);
}

// Round 14
// 66.878 us; speedup vs baseline: 1.2216x; 1.2216x over previous
//
#include <hip/hip_runtime.h>

// Problem constants (match reference)
#define BB 16
#define CC 8
#define HW (512 * 512)          // pixels per image
#define IGNORE_IDX 255
#define EPS_F 1e-5f
#define MINPIX 10.0f

// Launch config — stage 1 is LOOP-FREE: each thread handles exactly 4 pixels.
#define BPI 256                 // blocks per image
#define NTHR 256
#define NBLK (BB * BPI)         // 4096 stage-1 blocks
#define PPB (HW / BPI)          // 1024 pixels per block = 256 thr * 4 px

// ws layout (floats):
//   [0      .. 32768)   inter[b][c][chunk]   (16*8*256)
//   [32768  .. 65536)   psum [b][c][chunk]
//   [65536  .. 98304)   tsum [b][c][chunk]
//   [98304  .. 102400)  ce_partial[block]    (4096)
//   [102400 .. 106496)  cnt_partial[block]   (4096)
// Every slot is rewritten by stage1 each call -> no init needed.
#define OFF_INTER 0
#define OFF_PSUM  32768
#define OFF_TSUM  65536
#define OFF_CE    98304
#define OFF_CNT   (98304 + NBLK)

__device__ __forceinline__ float wave_red(float v) {
#pragma unroll
    for (int o = 32; o > 0; o >>= 1) v += __shfl_xor(v, o, 64);
    return v;
}

// NOTE (R8): no min-waves hint — __launch_bounds__(256,3) forced VGPR 232->84
// via scratch spills (+440 MB spill traffic, 8x slower).
// NOTE (R9/R11): latency-bound; capping in-flight loads to one iteration's 9
// dropped VGPR 232->48 and 76.9->49.6 us.
// NOTE (R7/R12): fusion closed. Fence-based tail = XCD-L2 writeback storm
// (5x); atomic-based tail = ~32 us serialized RMWs on 386 hot addresses.
// NOTE (R12->R13): loop removed entirely (BPI=256): the 2-iteration serial
// {load->drain->compute} chain per wave becomes pure block-level overlap.
__global__ __launch_bounds__(NTHR) void focal_stage1(
    const float* __restrict__ logits, const int* __restrict__ tgt,
    float* __restrict__ ws)
{
    const int b     = blockIdx.x / BPI;
    const int chunk = blockIdx.x % BPI;
    const float* base = logits + (size_t)b * (CC * HW);
    const int*   tb   = tgt    + (size_t)b * HW;
    const int pix = chunk * PPB + (int)threadIdx.x * 4;

    const int4 t4 = *reinterpret_cast<const int4*>(tb + pix);
    float4 v[8];
#pragma unroll
    for (int c = 0; c < 8; ++c)
        v[c] = *reinterpret_cast<const float4*>(base + (size_t)c * HW + pix);

    float psum[8]  = {0.f,0.f,0.f,0.f,0.f,0.f,0.f,0.f};
    float inter[8] = {0.f,0.f,0.f,0.f,0.f,0.f,0.f,0.f};
    int   tcnt[8]  = {0,0,0,0,0,0,0,0};
    float ce = 0.f;
    int   cnt = 0;

#pragma unroll
    for (int j = 0; j < 4; ++j) {
        const int t = (&t4.x)[j];
        float x[8];
#pragma unroll
        for (int c = 0; c < 8; ++c) x[c] = (&v[c].x)[j];

        float m = x[0];
#pragma unroll
        for (int c = 1; c < 8; ++c) m = fmaxf(m, x[c]);

        float e[8];
        float s = 0.f;
#pragma unroll
        for (int c = 0; c < 8; ++c) { e[c] = __expf(x[c] - m); s += e[c]; }
        const float inv = 1.0f / s;

        const bool valid = (t != IGNORE_IDX);
        float xt = 0.f, et = 0.f;
#pragma unroll
        for (int c = 0; c < 8; ++c) {
            const float pc = e[c] * inv;
            psum[c] += valid ? pc : 0.f;
            const bool hit = valid && (t == c);
            inter[c] += hit ? pc : 0.f;
            tcnt[c]  += hit ? 1 : 0;
            xt = (t == c) ? x[c] : xt;   // compile-time-unrolled select
            et = (t == c) ? e[c] : et;
        }
        const float pt    = et * inv;
        const float logpt = (xt - m) - __logf(s);
        const float omp   = 1.f - pt;
        ce  += valid ? -(omp * omp) * logpt : 0.f;
        cnt += valid ? 1 : 0;
    }

    // ---- block reduction: wave shuffle -> LDS -> single write per value ----
    __shared__ float sm[4][26];
    const int wave = threadIdx.x >> 6;
    const int lane = threadIdx.x & 63;

    float red[26];
#pragma unroll
    for (int c = 0; c < 8; ++c) red[c]      = inter[c];
#pragma unroll
    for (int c = 0; c < 8; ++c) red[8 + c]  = psum[c];
#pragma unroll
    for (int c = 0; c < 8; ++c) red[16 + c] = (float)tcnt[c];
    red[24] = ce;
    red[25] = (float)cnt;

#pragma unroll
    for (int k = 0; k < 26; ++k) {
        const float r = wave_red(red[k]);
        if (lane == 0) sm[wave][k] = r;
    }
    __syncthreads();

    const int tid = threadIdx.x;
    if (tid < 26) {
        const float tot = sm[0][tid] + sm[1][tid] + sm[2][tid] + sm[3][tid];
        if (tid < 8)
            ws[OFF_INTER + ((b * CC + tid) * BPI) + chunk] = tot;
        else if (tid < 16)
            ws[OFF_PSUM + ((b * CC + (tid - 8)) * BPI) + chunk] = tot;
        else if (tid < 24)
            ws[OFF_TSUM + ((b * CC + (tid - 16)) * BPI) + chunk] = tot;
        else if (tid == 24)
            ws[OFF_CE + blockIdx.x] = tot;
        else
            ws[OFF_CNT + blockIdx.x] = tot;
    }
}

// Stage 2: 1 block x 1024 threads. 8 threads per (b,c) pair, float4 reads.
#define NTHR2 1024

__global__ __launch_bounds__(NTHR2) void focal_stage2(
    const float* __restrict__ ws, float* __restrict__ out)
{
    const int tid  = threadIdx.x;
    const int wave = tid >> 6;
    const int lane = tid & 63;

    // ---- dice: pair = b*CC+c (128), 8 subthreads each sum 32 chunks (f4 x8)
    const int pair = tid >> 3;            // 0..127
    const int sub  = tid & 7;
    float I = 0.f, P = 0.f, T = 0.f;
    {
        const int off = pair * BPI + sub * (BPI / 8);   // 32-float, 16B aligned
#pragma unroll
        for (int k = 0; k < BPI / 8; k += 4) {
            const float4 i4 = *reinterpret_cast<const float4*>(&ws[OFF_INTER + off + k]);
            const float4 p4 = *reinterpret_cast<const float4*>(&ws[OFF_PSUM  + off + k]);
            const float4 t4 = *reinterpret_cast<const float4*>(&ws[OFF_TSUM  + off + k]);
            I += i4.x + i4.y + i4.z + i4.w;
            P += p4.x + p4.y + p4.z + p4.w;
            T += t4.x + t4.y + t4.z + t4.w;
        }
    }
#pragma unroll
    for (int o = 1; o < 8; o <<= 1) {     // combine the 8 subthreads (same wave)
        I += __shfl_xor(I, o, 64);
        P += __shfl_xor(P, o, 64);
        T += __shfl_xor(T, o, 64);
    }

    float dval = 0.f;
    const int c = pair & 7;
    if (sub == 0 && c >= 1 && T > MINPIX)
        dval = 1.f - (2.f * I + EPS_F) / (P + T + EPS_F);

    // ---- ce partials: 4096 floats each, one float4 per thread ----
    float ce, cn;
    {
        const float4 c4 = *reinterpret_cast<const float4*>(&ws[OFF_CE  + tid * 4]);
        const float4 n4 = *reinterpret_cast<const float4*>(&ws[OFF_CNT + tid * 4]);
        ce = c4.x + c4.y + c4.z + c4.w;
        cn = n4.x + n4.y + n4.z + n4.w;
    }

    dval = wave_red(dval);
    ce   = wave_red(ce);
    cn   = wave_red(cn);

    __shared__ float sd[3][16];
    if (lane == 0) { sd[0][wave] = dval; sd[1][wave] = ce; sd[2][wave] = cn; }
    __syncthreads();

    if (tid == 0) {
        float D = 0.f, CE = 0.f, CN = 0.f;
#pragma unroll
        for (int w = 0; w < 16; ++w) { D += sd[0][w]; CE += sd[1][w]; CN += sd[2][w]; }
        out[0] = (CE / CN) + 0.1f * (D / ((CC - 1) * (float)BB));
    }
}

extern "C" void kernel_launch(void* const* d_in, const int* in_sizes, int n_in,
                              void* d_out, int out_size, void* d_ws, size_t ws_size,
                              hipStream_t stream)
{
    const float* logits = (const float*)d_in[0];
    const int*   tgt    = (const int*)d_in[1];
    float*       ws     = (float*)d_ws;
    float*       out    = (float*)d_out;

    focal_stage1<<<NBLK, NTHR, 0, stream>>>(logits, tgt, ws);
    focal_stage2<<<1, NTHR2, 0, stream>>>(ws, out);
}